// Round 2
// baseline (541.517 us; speedup 1.0000x reference)
//
#include <hip/hip_runtime.h>
#include <hip/hip_bf16.h>

#define NB 32
#define NS 2048
#define DIM 1024
#define NM (NB*NS)   // 65536 rows

typedef __attribute__((ext_vector_type(8))) short short8;
typedef __attribute__((ext_vector_type(4))) float f32x4;
typedef unsigned short us16;
typedef unsigned int   u32;
typedef __attribute__((address_space(3))) void lds_void;
typedef __attribute__((address_space(1))) void glb_void;

__device__ __forceinline__ void gload16(const void* g, void* l){
  __builtin_amdgcn_global_load_lds((const glb_void*)g, (lds_void*)l, 16, 0, 0);
}

__device__ __forceinline__ float fast_tanh(float x){
  float e = __builtin_exp2f(x * 2.8853900817779268f); // e^{2x}
  return 1.0f - 2.0f/(e + 1.0f);
}

// split f32 into bf16 hi (truncated) + bf16 lo (residual); rep error ~2^-16 rel
__device__ __forceinline__ void split_bf16(float x, short &hi, short &lo){
  u32 u = __float_as_uint(x);
  float hf = __uint_as_float(u & 0xFFFF0000u);
  hi = (short)(u >> 16);
  lo = (short)(__float_as_uint(x - hf) >> 16);
}

// ---------------- Wb -> pre-swizzled hi|lo image for global_load_lds ----------
// image = [ct(8)][kt(32)][16384B tile]; LDS byte b of a tile holds element
// j = ((b&127) ^ ((r&7)<<4))>>1 of row r=b>>7  (j<32: hi(wb), j>=32: lo(wb))
__global__ void k_split_wb(const float* __restrict__ wb, char* __restrict__ img){
  const int tid = blockIdx.x*256 + threadIdx.x;       // 262144 threads, 16B each
  const int tt = tid >> 10;                           // tile index (1024 chunks/tile)
  const int ct = tt >> 5, kt = tt & 31;
  const int b14 = (tid & 1023) * 16;                  // tile-local byte offset
  const int r  = b14 >> 7, c = b14 & 127;
  const int j0 = (c ^ ((r & 7) << 4)) >> 1;           // multiple of 8
  const float* src = wb + (size_t)(ct*128 + r)*DIM + kt*32 + (j0 & 31);
  float4 v0 = *(const float4*)src;
  float4 v1 = *(const float4*)(src + 4);
  float fv[8] = {v0.x,v0.y,v0.z,v0.w,v1.x,v1.y,v1.z,v1.w};
  short8 out;
  const bool lohalf = (j0 >= 32);
  #pragma unroll
  for(int j=0;j<8;j++){
    short hi,lo; split_bf16(fv[j],hi,lo);
    out[j] = lohalf ? lo : hi;
  }
  *(short8*)(img + (size_t)tid*16) = out;
}

// ---------------- a = k @ Wa^T ----------------
__global__ void k_compute_a(const float* __restrict__ kin,
                            const float* __restrict__ wa,
                            float* __restrict__ avec){
  __shared__ float4 kl[256];
  const int b = blockIdx.x >> 2, oc = blockIdx.x & 3;
  const int t = threadIdx.x;
  kl[t] = *(const float4*)(kin + b*DIM + t*4);
  __syncthreads();
  const int o = oc*256 + t;
  const float4* wrow = (const float4*)(wa + (size_t)o*DIM);
  float acc = 0.f;
  for(int i=0;i<256;i++){
    float4 wv = wrow[i]; float4 kk = kl[i];
    acc += wv.x*kk.x + wv.y*kk.y + wv.z*kk.z + wv.w*kk.w;
  }
  avec[b*DIM + o] = acc;
}

// ---------------- main GEMM + fused tanh/energy epilogue ----------------
__global__ __launch_bounds__(256,3)
void k_gemm_scores(const float* __restrict__ xs,
                   const char* __restrict__ wbimg,
                   const float* __restrict__ avec,
                   const float* __restrict__ energy,
                   float* __restrict__ partial){
  __shared__ us16 Abuf[128][64];      // hi cols 0..31 | lo cols 32..63, swizzled
  __shared__ us16 Bbuf[2][128][64];   // double-buffered, filled by global_load_lds

  const int h  = blockIdx.x;
  const int rt = (h & 7) + 8*(h >> 6);       // same-rt blocks share an XCD (L2 A-reuse)
  const int ct = (h >> 3) & 7;
  const int t  = threadIdx.x;
  const int w  = t >> 6, lane = t & 63;
  const int wr = w >> 1, wc = w & 1;
  const int lm = lane & 15, lk = lane >> 4;
  const int sr = t >> 1, sh = t & 1;

  const float* ap   = xs + (size_t)(rt*128 + sr)*DIM + sh*16;
  const char*  bsrc = wbimg + ((size_t)ct << 19);     // ct * 32 tiles * 16KB

  f32x4 acc[4][4];
  #pragma unroll
  for(int m=0;m<4;m++)
    #pragma unroll
    for(int n=0;n<4;n++) acc[m][n] = (f32x4){0.f,0.f,0.f,0.f};

  // issue B(0) (before A loads: keeps B older in the vmcnt queue)
  {
    const char* gs = bsrc + w*4096 + lane*16;
    char* ld = (char*)&Bbuf[0][0][0] + w*4096;
    gload16(gs, ld); gload16(gs+1024, ld+1024);
    gload16(gs+2048, ld+2048); gload16(gs+3072, ld+3072);
  }
  float4 ar0 = *(const float4*)(ap+0),  ar1 = *(const float4*)(ap+4);
  float4 ar2 = *(const float4*)(ap+8),  ar3 = *(const float4*)(ap+12);

  for(int kt=0; kt<32; kt++){
    const int cur = kt & 1, nxt = cur ^ 1;
    __syncthreads();                      // bar1: all frag reads of prior iter done
    {                                     // split A(kt) -> swizzled LDS
      float fv[16];
      *(float4*)(fv+0)=ar0; *(float4*)(fv+4)=ar1;
      *(float4*)(fv+8)=ar2; *(float4*)(fv+12)=ar3;
      short8 h0,h1,l0,l1;
      #pragma unroll
      for(int j=0;j<8;j++){ short a,b; split_bf16(fv[j],a,b);   h0[j]=a; l0[j]=b; }
      #pragma unroll
      for(int j=0;j<8;j++){ short a,b; split_bf16(fv[8+j],a,b); h1[j]=a; l1[j]=b; }
      const int swz = (sr & 7) << 4;
      char* abase = (char*)&Abuf[0][0] + sr*128;
      *(short8*)(abase + ((sh*32      ) ^ swz)) = h0;
      *(short8*)(abase + ((sh*32 + 16 ) ^ swz)) = h1;
      *(short8*)(abase + ((64 + sh*32     ) ^ swz)) = l0;
      *(short8*)(abase + ((64 + sh*32 + 16) ^ swz)) = l1;
    }
    if(kt < 31){
      {                                   // issue B(kt+1) into other buffer (safe after bar1)
        const char* gs = bsrc + ((kt+1) << 14) + w*4096 + lane*16;
        char* ld = (char*)&Bbuf[nxt][0][0] + w*4096;
        gload16(gs, ld); gload16(gs+1024, ld+1024);
        gload16(gs+2048, ld+2048); gload16(gs+3072, ld+3072);
      }
      const float* a2 = ap + (kt+1)*32;   // prefetch A(kt+1)
      ar0 = *(const float4*)(a2+0);  ar1 = *(const float4*)(a2+4);
      ar2 = *(const float4*)(a2+8);  ar3 = *(const float4*)(a2+12);
    }
    // ensure B(kt) landed: allow only the 8 just-issued loads to remain in flight
    if(kt < 31) asm volatile("s_waitcnt vmcnt(8)" ::: "memory");
    else        asm volatile("s_waitcnt vmcnt(0)" ::: "memory");
    __builtin_amdgcn_sched_barrier(0);
    __syncthreads();                      // bar2: LDS tile ready

    short8 fah[4], fal[4], fbh[4], fbl[4];
    const char* ab = (const char*)&Abuf[0][0];
    const char* bb = (const char*)&Bbuf[cur][0][0];
    #pragma unroll
    for(int m=0;m<4;m++){
      const int r = wr*64 + m*16 + lm, sw = (r&7)<<4, rb = r*128;
      fah[m] = *(const short8*)(ab + rb + ((lk*16) ^ sw));
      fal[m] = *(const short8*)(ab + rb + ((64 + lk*16) ^ sw));
    }
    #pragma unroll
    for(int n=0;n<4;n++){
      const int r = wc*64 + n*16 + lm, sw = (r&7)<<4, rb = r*128;
      fbh[n] = *(const short8*)(bb + rb + ((lk*16) ^ sw));
      fbl[n] = *(const short8*)(bb + rb + ((64 + lk*16) ^ sw));
    }
    // pass-outer order: 16 independent MFMAs between same-acc reuses
    #pragma unroll
    for(int m=0;m<4;m++)
      #pragma unroll
      for(int n=0;n<4;n++)
        acc[m][n] = __builtin_amdgcn_mfma_f32_16x16x32_bf16(fah[m], fbh[n], acc[m][n], 0,0,0);
    #pragma unroll
    for(int m=0;m<4;m++)
      #pragma unroll
      for(int n=0;n<4;n++)
        acc[m][n] = __builtin_amdgcn_mfma_f32_16x16x32_bf16(fah[m], fbl[n], acc[m][n], 0,0,0);
    #pragma unroll
    for(int m=0;m<4;m++)
      #pragma unroll
      for(int n=0;n<4;n++)
        acc[m][n] = __builtin_amdgcn_mfma_f32_16x16x32_bf16(fal[m], fbh[n], acc[m][n], 0,0,0);
  }

  // ---- epilogue: partial[ct][row] = sum_{o in ct-tile} energy[o]*tanh(a[o]+b) ----
  const int bidx = (rt*128)/NS;
  float av[4], ev[4];
  #pragma unroll
  for(int n=0;n<4;n++){
    const int col = ct*128 + wc*64 + n*16 + lm;
    av[n] = avec[bidx*DIM + col];
    ev[n] = energy[col];
  }
  float rs[4][4];
  #pragma unroll
  for(int m=0;m<4;m++)
    #pragma unroll
    for(int j=0;j<4;j++){
      float s = 0.f;
      #pragma unroll
      for(int n=0;n<4;n++) s += ev[n]*fast_tanh(av[n] + acc[m][n][j]);
      s += __shfl_xor(s,1); s += __shfl_xor(s,2);
      s += __shfl_xor(s,4); s += __shfl_xor(s,8);
      rs[m][j] = s;
    }
  float* srow = (float*)&Abuf[0][0];
  __syncthreads();
  if(wc==0 && lm==0){
    #pragma unroll
    for(int m=0;m<4;m++)
      #pragma unroll
      for(int j=0;j<4;j++) srow[wr*64+m*16+lk*4+j] = rs[m][j];
  }
  __syncthreads();
  if(wc==1 && lm==0){
    #pragma unroll
    for(int m=0;m<4;m++)
      #pragma unroll
      for(int j=0;j<4;j++) srow[wr*64+m*16+lk*4+j] += rs[m][j];
  }
  __syncthreads();
  if(t < 128) partial[(size_t)ct*NM + rt*128 + t] = srow[t];
}

// ---------------- fused: reduce 8 partials + masked softmax ----------------
__global__ void k_softmax(const float* __restrict__ partial,
                          const int* __restrict__ mask,
                          float* __restrict__ attn){
  const int b = blockIdx.x, t = threadIdx.x;
  const int w = t >> 6, lane = t & 63;
  __shared__ float red[4];
  float sv[8]; int mv[8];
  float m = -3.4e38f;
  #pragma unroll
  for(int j=0;j<8;j++){
    const int i = j*256 + t;
    float s = 0.f;
    #pragma unroll
    for(int c=0;c<8;c++) s += partial[(size_t)c*NM + b*NS + i];
    sv[j] = s;
    mv[j] = mask[b*NS + i];
    if(mv[j] && s > m) m = s;
  }
  #pragma unroll
  for(int off=1; off<64; off<<=1) m = fmaxf(m, __shfl_xor(m, off));
  if(lane==0) red[w] = m;
  __syncthreads();
  m = fmaxf(fmaxf(red[0],red[1]), fmaxf(red[2],red[3]));
  __syncthreads();
  float ev[8]; float l = 0.f;
  #pragma unroll
  for(int j=0;j<8;j++){
    ev[j] = mv[j] ? __builtin_exp2f((sv[j]-m)*1.4426950408889634f) : 0.f;
    l += ev[j];
  }
  #pragma unroll
  for(int off=1; off<64; off<<=1) l += __shfl_xor(l, off);
  if(lane==0) red[w] = l;
  __syncthreads();
  l = red[0]+red[1]+red[2]+red[3];
  const float inv = 1.0f/l;
  #pragma unroll
  for(int j=0;j<8;j++) attn[b*NS + j*256 + t] = ev[j]*inv;
}

// ---------------- ctx = attn @ xs (skip negligible attn rows) ----------------
__global__ void k_ctx(const float* __restrict__ attn,
                      const float* __restrict__ xs,
                      float* __restrict__ ctx){
  const int b = blockIdx.x, t = threadIdx.x;
  __shared__ float al[NS];
  #pragma unroll
  for(int j=0;j<8;j++) al[j*256+t] = attn[b*NS + j*256 + t];
  __syncthreads();
  float4 acc = {0.f,0.f,0.f,0.f};
  const float* xb = xs + (size_t)b*NS*DIM + t*4;
  for(int s=0;s<NS;s++){
    const float wv = al[s];                 // uniform across block
    if(wv > 1e-12f){                        // contribution < 1e-8, deterministic
      const float4 x = *(const float4*)(xb + (size_t)s*DIM);
      acc.x += wv*x.x; acc.y += wv*x.y; acc.z += wv*x.z; acc.w += wv*x.w;
    }
  }
  *(float4*)(ctx + b*DIM + t*4) = acc;
}

extern "C" void kernel_launch(void* const* d_in, const int* in_sizes, int n_in,
                              void* d_out, int out_size, void* d_ws, size_t ws_size,
                              hipStream_t stream) {
  const float* kin    = (const float*)d_in[0];   // [32,1024]
  const float* xs     = (const float*)d_in[1];   // [32,2048,1024]
  const int*   mask   = (const int*)d_in[2];     // [32,2048]
  const float* wa     = (const float*)d_in[3];   // [1024,1024]
  const float* wb     = (const float*)d_in[4];   // [1024,1024]
  const float* energy = (const float*)d_in[5];   // [1024]
  float* out  = (float*)d_out;
  float* ctx  = out;            // [32,1024]
  float* attn = out + NB*DIM;   // [32,2048]

  char* ws = (char*)d_ws;
  float* partial = (float*)(ws);                      // 8*65536*4 = 2 MB
  float* avec    = (float*)(ws + 2097152);            // 128 KB
  char*  wbimg   = ws + 2097152 + 131072;             // 4 MB pre-swizzled image

  k_split_wb   <<<1024, 256, 0, stream>>>(wb, wbimg);
  k_compute_a  <<<128, 256, 0, stream>>>(kin, wa, avec);
  k_gemm_scores<<<4096, 256, 0, stream>>>(xs, wbimg, avec, energy, partial);
  k_softmax    <<<NB, 256, 0, stream>>>(partial, mask, attn);
  k_ctx        <<<NB, 256, 0, stream>>>(attn, xs, ctx);
}

// Round 3
// 412.786 us; speedup vs baseline: 1.3119x; 1.3119x over previous
//
#include <hip/hip_runtime.h>
#include <hip/hip_bf16.h>

#define NB 32
#define NS 2048
#define DIM 1024
#define NM (NB*NS)   // 65536 rows

typedef __attribute__((ext_vector_type(8))) short short8;
typedef __attribute__((ext_vector_type(4))) float f32x4;
typedef unsigned short us16;
typedef unsigned int   u32;
typedef __attribute__((address_space(3))) void lds_void;
typedef __attribute__((address_space(1))) void glb_void;

__device__ __forceinline__ void gload16(const void* g, void* l){
  __builtin_amdgcn_global_load_lds((const glb_void*)g, (lds_void*)l, 16, 0, 0);
}

__device__ __forceinline__ float fast_tanh(float x){
  float e = __builtin_exp2f(x * 2.8853900817779268f); // e^{2x}
  return 1.0f - 2.0f/(e + 1.0f);
}

// split f32 into bf16 hi (truncated) + bf16 lo (residual); rep error ~2^-16 rel
__device__ __forceinline__ void split_bf16(float x, short &hi, short &lo){
  u32 u = __float_as_uint(x);
  float hf = __uint_as_float(u & 0xFFFF0000u);
  hi = (short)(u >> 16);
  lo = (short)(__float_as_uint(x - hf) >> 16);
}

// ---------------- Wb -> pre-swizzled hi|lo image for global_load_lds ----------
// image = [kt(32)][ct128(8)][16384B tile]; within a tile, byte b holds element
// j = ((b&127) ^ ((r&7)<<4))>>1 of row r=b>>7  (j<32: hi(wb), j>=32: lo(wb))
// [kt][ct] major so a 256-row (two-ct) B tile at fixed kt is contiguous 32KB.
__global__ void k_split_wb(const float* __restrict__ wb, char* __restrict__ img){
  const int tid = blockIdx.x*256 + threadIdx.x;       // 262144 threads, 16B each
  const int tt = tid >> 10;                           // tile index (1024 chunks/tile)
  const int kt = tt >> 3, ct = tt & 7;
  const int b14 = (tid & 1023) * 16;                  // tile-local byte offset
  const int r  = b14 >> 7, c = b14 & 127;
  const int j0 = (c ^ ((r & 7) << 4)) >> 1;           // multiple of 8
  const float* src = wb + (size_t)(ct*128 + r)*DIM + kt*32 + (j0 & 31);
  float4 v0 = *(const float4*)src;
  float4 v1 = *(const float4*)(src + 4);
  float fv[8] = {v0.x,v0.y,v0.z,v0.w,v1.x,v1.y,v1.z,v1.w};
  short8 out;
  const bool lohalf = (j0 >= 32);
  #pragma unroll
  for(int j=0;j<8;j++){
    short hi,lo; split_bf16(fv[j],hi,lo);
    out[j] = lohalf ? lo : hi;
  }
  *(short8*)(img + (size_t)tid*16) = out;
}

// ---------------- a = k @ Wa^T ----------------
__global__ void k_compute_a(const float* __restrict__ kin,
                            const float* __restrict__ wa,
                            float* __restrict__ avec){
  __shared__ float4 kl[256];
  const int b = blockIdx.x >> 2, oc = blockIdx.x & 3;
  const int t = threadIdx.x;
  kl[t] = *(const float4*)(kin + b*DIM + t*4);
  __syncthreads();
  const int o = oc*256 + t;
  const float4* wrow = (const float4*)(wa + (size_t)o*DIM);
  float acc = 0.f;
  for(int i=0;i<256;i++){
    float4 wv = wrow[i]; float4 kk = kl[i];
    acc += wv.x*kk.x + wv.y*kk.y + wv.z*kk.z + wv.w*kk.w;
  }
  avec[b*DIM + o] = acc;
}

// ---------------- main GEMM (128x256 tile) + fused tanh/energy epilogue -------
__global__ __launch_bounds__(256,2)
void k_gemm_scores(const float* __restrict__ xs,
                   const char* __restrict__ wbimg,
                   const float* __restrict__ avec,
                   const float* __restrict__ energy,
                   float* __restrict__ partial){
  __shared__ us16 Abuf[128][64];      // hi cols 0..31 | lo 32..63, XOR-swizzled
  __shared__ us16 Bbuf[2][256][64];   // double-buffered, filled by global_load_lds

  const int h  = blockIdx.x;                  // 2048 blocks
  const int rt = (h & 7) + 8*(h >> 5);        // same-rt blocks on same XCD (A L2 reuse)
  const int cb = (h >> 3) & 3;                // 256-col tile index
  const int t  = threadIdx.x;
  const int w  = t >> 6, lane = t & 63;
  const int wr = w >> 1, wc = w & 1;          // wave tile: 64 rows x 128 cols
  const int lm = lane & 15, lk = lane >> 4;
  const int sr = t >> 1, sh = t & 1;

  const float* ap   = xs + (size_t)(rt*128 + sr)*DIM + sh*16;
  const char*  bsrc = wbimg + cb*32768;       // + kt*131072 per K-step

  f32x4 acc[4][8];
  #pragma unroll
  for(int m=0;m<4;m++)
    #pragma unroll
    for(int n=0;n<8;n++) acc[m][n] = (f32x4){0.f,0.f,0.f,0.f};

  // issue B(0): 32KB via 8 gloads/thread
  {
    const char* gs = bsrc + w*8192 + lane*16;
    char* ld = (char*)&Bbuf[0][0][0] + w*8192;
    #pragma unroll
    for(int cch=0; cch<8; cch++) gload16(gs + cch*1024, ld + cch*1024);
  }
  float4 ar0 = *(const float4*)(ap+0),  ar1 = *(const float4*)(ap+4);
  float4 ar2 = *(const float4*)(ap+8),  ar3 = *(const float4*)(ap+12);

  for(int kt=0; kt<32; kt++){
    const int cur = kt & 1, nxt = cur ^ 1;
    __syncthreads();                      // bar1: prior iter's frag reads done
    {                                     // split A(kt) -> swizzled LDS
      float fv[16];
      *(float4*)(fv+0)=ar0; *(float4*)(fv+4)=ar1;
      *(float4*)(fv+8)=ar2; *(float4*)(fv+12)=ar3;
      short8 h0,h1,l0,l1;
      #pragma unroll
      for(int j=0;j<8;j++){ short a,b; split_bf16(fv[j],a,b);   h0[j]=a; l0[j]=b; }
      #pragma unroll
      for(int j=0;j<8;j++){ short a,b; split_bf16(fv[8+j],a,b); h1[j]=a; l1[j]=b; }
      const int swz = (sr & 7) << 4;
      char* abase = (char*)&Abuf[0][0] + sr*128;
      *(short8*)(abase + ((sh*32      ) ^ swz)) = h0;
      *(short8*)(abase + ((sh*32 + 16 ) ^ swz)) = h1;
      *(short8*)(abase + ((64 + sh*32     ) ^ swz)) = l0;
      *(short8*)(abase + ((64 + sh*32 + 16) ^ swz)) = l1;
    }
    if(kt < 31){
      const float* a2 = ap + (kt+1)*32;   // prefetch A(kt+1) -> regs (4 vmem)
      ar0 = *(const float4*)(a2+0);  ar1 = *(const float4*)(a2+4);
      ar2 = *(const float4*)(a2+8);  ar3 = *(const float4*)(a2+12);
      {                                   // issue B(kt+1) (8 vmem), safe after bar1
        const char* gs = bsrc + (kt+1)*131072 + w*8192 + lane*16;
        char* ld = (char*)&Bbuf[nxt][0][0] + w*8192;
        #pragma unroll
        for(int cch=0; cch<8; cch++) gload16(gs + cch*1024, ld + cch*1024);
      }
      // exactly the 12 just-issued ops may stay in flight; B(kt) must be done
      asm volatile("s_waitcnt vmcnt(12)" ::: "memory");
    } else {
      asm volatile("s_waitcnt vmcnt(0)" ::: "memory");
    }
    __builtin_amdgcn_sched_barrier(0);
    __syncthreads();                      // bar2: LDS tile kt ready

    short8 fah[4], fal[4];
    const char* ab = (const char*)&Abuf[0][0];
    const char* bb = (const char*)&Bbuf[cur][0][0];
    #pragma unroll
    for(int m=0;m<4;m++){
      const int r = wr*64 + m*16 + lm, sw = (r&7)<<4, rb = r*128;
      fah[m] = *(const short8*)(ab + rb + ((lk*16) ^ sw));
      fal[m] = *(const short8*)(ab + rb + ((64 + lk*16) ^ sw));
    }
    #pragma unroll
    for(int half=0; half<2; half++){      // two n-halves: keeps B frags at 32 VGPR
      short8 fbh[4], fbl[4];
      #pragma unroll
      for(int n=0;n<4;n++){
        const int r = wc*128 + (half*4+n)*16 + lm, sw = (r&7)<<4, rb = r*128;
        fbh[n] = *(const short8*)(bb + rb + ((lk*16) ^ sw));
        fbl[n] = *(const short8*)(bb + rb + ((64 + lk*16) ^ sw));
      }
      #pragma unroll
      for(int m=0;m<4;m++)
        #pragma unroll
        for(int n=0;n<4;n++)
          acc[m][half*4+n] = __builtin_amdgcn_mfma_f32_16x16x32_bf16(fah[m], fbh[n], acc[m][half*4+n], 0,0,0);
      #pragma unroll
      for(int m=0;m<4;m++)
        #pragma unroll
        for(int n=0;n<4;n++)
          acc[m][half*4+n] = __builtin_amdgcn_mfma_f32_16x16x32_bf16(fah[m], fbl[n], acc[m][half*4+n], 0,0,0);
      #pragma unroll
      for(int m=0;m<4;m++)
        #pragma unroll
        for(int n=0;n<4;n++)
          acc[m][half*4+n] = __builtin_amdgcn_mfma_f32_16x16x32_bf16(fal[m], fbh[n], acc[m][half*4+n], 0,0,0);
    }
  }

  // ---- epilogue: partial[2cb+wc][row] = sum over this wave's 128 cols ----
  const int bidx = rt >> 4;               // rt*128/NS
  float av[8], ev[8];
  #pragma unroll
  for(int n=0;n<8;n++){
    const int col = cb*256 + wc*128 + n*16 + lm;
    av[n] = avec[bidx*DIM + col];
    ev[n] = energy[col];
  }
  #pragma unroll
  for(int m=0;m<4;m++){
    float rs[4];
    #pragma unroll
    for(int j=0;j<4;j++){
      float s = 0.f;
      #pragma unroll
      for(int n=0;n<8;n++) s += ev[n]*fast_tanh(av[n] + acc[m][n][j]);
      s += __shfl_xor(s,1); s += __shfl_xor(s,2);
      s += __shfl_xor(s,4); s += __shfl_xor(s,8);
      rs[j] = s;
    }
    if(lm == 0){                          // lanes 0,16,32,48: rows lk*4..lk*4+3
      float4 st = {rs[0], rs[1], rs[2], rs[3]};
      *(float4*)(partial + (size_t)(2*cb+wc)*NM + rt*128 + wr*64 + m*16 + lk*4) = st;
    }
  }
}

// ---------------- fused: reduce 8 partials + masked softmax ----------------
__global__ void k_softmax(const float* __restrict__ partial,
                          const int* __restrict__ mask,
                          float* __restrict__ attn){
  const int b = blockIdx.x, t = threadIdx.x;
  const int w = t >> 6, lane = t & 63;
  __shared__ float red[4];
  float sv[8]; int mv[8];
  float m = -3.4e38f;
  #pragma unroll
  for(int j=0;j<8;j++){
    const int i = j*256 + t;
    float s = 0.f;
    #pragma unroll
    for(int c=0;c<8;c++) s += partial[(size_t)c*NM + b*NS + i];
    sv[j] = s;
    mv[j] = mask[b*NS + i];
    if(mv[j] && s > m) m = s;
  }
  #pragma unroll
  for(int off=1; off<64; off<<=1) m = fmaxf(m, __shfl_xor(m, off));
  if(lane==0) red[w] = m;
  __syncthreads();
  m = fmaxf(fmaxf(red[0],red[1]), fmaxf(red[2],red[3]));
  __syncthreads();
  float ev[8]; float l = 0.f;
  #pragma unroll
  for(int j=0;j<8;j++){
    ev[j] = mv[j] ? __builtin_exp2f((sv[j]-m)*1.4426950408889634f) : 0.f;
    l += ev[j];
  }
  #pragma unroll
  for(int off=1; off<64; off<<=1) l += __shfl_xor(l, off);
  if(lane==0) red[w] = l;
  __syncthreads();
  l = red[0]+red[1]+red[2]+red[3];
  const float inv = 1.0f/l;
  #pragma unroll
  for(int j=0;j<8;j++) attn[b*NS + j*256 + t] = ev[j]*inv;
}

// ---------------- ctx = attn @ xs, chunked (256 blocks) ----------------
__global__ void k_ctx_partial(const float* __restrict__ attn,
                              const float* __restrict__ xs,
                              float* __restrict__ cp){
  const int b = blockIdx.x >> 3, ch = blockIdx.x & 7;
  const int t = threadIdx.x;
  __shared__ float al[256];
  al[t] = attn[b*NS + ch*256 + t];
  __syncthreads();
  float4 acc = {0.f,0.f,0.f,0.f};
  const float* base = xs + (size_t)(b*NS + ch*256)*DIM + t*4;
  for(int i=0;i<256;i++){
    float wv = al[i];                 // uniform across block -> no divergence
    if(wv > 1e-12f){                  // contribution bound < 1e-8, deterministic
      float4 x = *(const float4*)(base + (size_t)i*DIM);
      acc.x += wv*x.x; acc.y += wv*x.y; acc.z += wv*x.z; acc.w += wv*x.w;
    }
  }
  *(float4*)(cp + ((size_t)ch*NB + b)*DIM + t*4) = acc;
}

__global__ void k_ctx_reduce(const float* __restrict__ cp, float* __restrict__ ctx){
  int i = blockIdx.x*256 + threadIdx.x;
  float s = 0.f;
  #pragma unroll
  for(int ch=0; ch<8; ch++) s += cp[(size_t)ch*NB*DIM + i];
  ctx[i] = s;
}

extern "C" void kernel_launch(void* const* d_in, const int* in_sizes, int n_in,
                              void* d_out, int out_size, void* d_ws, size_t ws_size,
                              hipStream_t stream) {
  const float* kin    = (const float*)d_in[0];   // [32,1024]
  const float* xs     = (const float*)d_in[1];   // [32,2048,1024]
  const int*   mask   = (const int*)d_in[2];     // [32,2048]
  const float* wa     = (const float*)d_in[3];   // [1024,1024]
  const float* wb     = (const float*)d_in[4];   // [1024,1024]
  const float* energy = (const float*)d_in[5];   // [1024]
  float* out  = (float*)d_out;
  float* ctx  = out;            // [32,1024]
  float* attn = out + NB*DIM;   // [32,2048]

  char* ws = (char*)d_ws;
  float* partial = (float*)(ws);                        // 8*65536*4 = 2 MB
  float* avec    = (float*)(ws + 2097152);              // 128 KB
  float* cp      = (float*)(ws + 2097152 + 131072);     // 8*32*1024*4 = 1 MB
  char*  wbimg   = ws + 2097152 + 131072 + 1048576;     // 4 MB pre-swizzled image

  k_split_wb   <<<1024, 256, 0, stream>>>(wb, wbimg);
  k_compute_a  <<<128, 256, 0, stream>>>(kin, wa, avec);
  k_gemm_scores<<<2048, 256, 0, stream>>>(xs, wbimg, avec, energy, partial);
  k_softmax    <<<NB, 256, 0, stream>>>(partial, mask, attn);
  k_ctx_partial<<<256, 256, 0, stream>>>(attn, xs, cp);
  k_ctx_reduce <<<128, 256, 0, stream>>>(cp, ctx);
}